// Round 1
// baseline (585.778 us; speedup 1.0000x reference)
//
#include <hip/hip_runtime.h>
#include <cstdint>
#include <cstddef>

#define VAR0_ 0.1f
#define VAR1_ 0.2f
#define KTOP_ 5
#define T1_ 0.35f
#define T2_ 0.5f
#define ALPHA_ 0.25f
#define BETA_ 0.11f
#define BS 256

__device__ __forceinline__ float iou_box(float ax1, float ay1, float ax2, float ay2,
                                         float bx1, float by1, float bx2, float by2) {
    float lx = fmaxf(ax1, bx1), ly = fmaxf(ay1, by1);
    float rx = fminf(ax2, bx2), ry = fminf(ay2, by2);
    float w = fmaxf(rx - lx, 0.f), h = fmaxf(ry - ly, 0.f);
    float inter = w * h;
    float aa = (ax2 - ax1) * (ay2 - ay1);
    float ab = (bx2 - bx1) * (by2 - by1);
    return inter / (aa + ab - inter);
}

__device__ __forceinline__ float sl1(float d) {
    float x = fabsf(d);
    return (x >= BETA_) ? (x - 0.5f * BETA_) : (0.5f * x * x / BETA_);
}

// ---------------- K0: zero candidate counters ----------------
__global__ void k_zero(int* __restrict__ cand_cnt, int n) {
    int i = blockIdx.x * blockDim.x + threadIdx.x;
    if (i < n) cand_cnt[i] = 0;
}

// ---------------- K1: per-prior column maxes + decode + candidate harvest ----------------
__global__ void k_per_prior(const float* __restrict__ loc, const float* __restrict__ priors,
                            const float* __restrict__ targets,
                            float* __restrict__ bt_score, int* __restrict__ bt_idx,
                            float* __restrict__ cb_score, int* __restrict__ cb_idx,
                            float* __restrict__ c_score,
                            float* __restrict__ cand_v, int* __restrict__ cand_i,
                            int* __restrict__ cand_cnt,
                            int P, int N, int CAP) {
    int b = blockIdx.y;
    int i = blockIdx.x * blockDim.x + threadIdx.x;
    __shared__ float tr[64 * 4];
    for (int t = threadIdx.x; t < N; t += blockDim.x) {
        tr[t * 4 + 0] = targets[(size_t)(b * N + t) * 5 + 0];
        tr[t * 4 + 1] = targets[(size_t)(b * N + t) * 5 + 1];
        tr[t * 4 + 2] = targets[(size_t)(b * N + t) * 5 + 2];
        tr[t * 4 + 3] = targets[(size_t)(b * N + t) * 5 + 3];
    }
    __syncthreads();
    if (i >= P) return;

    float pcx = priors[(size_t)i * 4 + 0], pcy = priors[(size_t)i * 4 + 1];
    float pw = priors[(size_t)i * 4 + 2], ph = priors[(size_t)i * 4 + 3];
    float px1 = pcx - pw * 0.5f, py1 = pcy - ph * 0.5f;
    float px2 = pcx + pw * 0.5f, py2 = pcy + ph * 0.5f;

    // stage-1: max over truths of IoU(truth, prior_pt); first-max tiebreak (n ascending, strict >)
    float bv = -1.f; int bn = 0;
    for (int n = 0; n < N; n++) {
        float v = iou_box(tr[n * 4 + 0], tr[n * 4 + 1], tr[n * 4 + 2], tr[n * 4 + 3],
                          px1, py1, px2, py2);
        if (v > bv) { bv = v; bn = n; }
    }

    // decode(loc, prior)
    size_t bp = (size_t)b * P + i;
    float l0 = loc[bp * 4 + 0], l1 = loc[bp * 4 + 1], l2 = loc[bp * 4 + 2], l3 = loc[bp * 4 + 3];
    float dcx = pcx + l0 * VAR0_ * pw;
    float dcy = pcy + l1 * VAR0_ * ph;
    float dw = pw * expf(l2 * VAR1_);
    float dh = ph * expf(l3 * VAR1_);
    float dx1 = dcx - dw * 0.5f, dy1 = dcy - dh * 0.5f;
    float dx2 = dcx + dw * 0.5f, dy2 = dcy + dh * 0.5f;

    // stage-2: max over truths of IoU(truth, decoded); harvest candidates >= T2
    float cv = -1.f; int cn = 0;
    for (int n = 0; n < N; n++) {
        float v = iou_box(tr[n * 4 + 0], tr[n * 4 + 1], tr[n * 4 + 2], tr[n * 4 + 3],
                          dx1, dy1, dx2, dy2);
        if (v > cv) { cv = v; cn = n; }
        if (v >= T2_) {
            int pos = atomicAdd(&cand_cnt[b * N + n], 1);
            if (pos < CAP) {
                size_t o = (size_t)(b * N + n) * CAP + pos;
                cand_v[o] = v; cand_i[o] = i;
            }
        }
    }
    bt_score[bp] = bv; bt_idx[bp] = bn;
    cb_score[bp] = cv; cb_idx[bp] = cn;
    c_score[bp] = 0.f;
}

// ---------------- K1b: per-(b,n) row max/argmax over all priors ----------------
__global__ void k_row_max(const float* __restrict__ priors, const float* __restrict__ targets,
                          float* __restrict__ row_max, int* __restrict__ row_arg,
                          int P, int N) {
    int n = blockIdx.x, b = blockIdx.y;
    float tx1 = targets[(size_t)(b * N + n) * 5 + 0];
    float ty1 = targets[(size_t)(b * N + n) * 5 + 1];
    float tx2 = targets[(size_t)(b * N + n) * 5 + 2];
    float ty2 = targets[(size_t)(b * N + n) * 5 + 3];
    float bv = -1.f; int bi = 0x7fffffff;
    for (int i = threadIdx.x; i < P; i += blockDim.x) {
        float pcx = priors[(size_t)i * 4 + 0], pcy = priors[(size_t)i * 4 + 1];
        float pw = priors[(size_t)i * 4 + 2], ph = priors[(size_t)i * 4 + 3];
        float v = iou_box(tx1, ty1, tx2, ty2,
                          pcx - pw * 0.5f, pcy - ph * 0.5f, pcx + pw * 0.5f, pcy + ph * 0.5f);
        if (v > bv) { bv = v; bi = i; }
    }
    __shared__ float sv[BS];
    __shared__ int si[BS];
    int tid = threadIdx.x;
    sv[tid] = bv; si[tid] = bi;
    __syncthreads();
    for (int s = BS / 2; s > 0; s >>= 1) {
        if (tid < s) {
            if (sv[tid + s] > sv[tid] || (sv[tid + s] == sv[tid] && si[tid + s] < si[tid])) {
                sv[tid] = sv[tid + s]; si[tid] = si[tid + s];
            }
        }
        __syncthreads();
    }
    if (tid == 0) { row_max[b * N + n] = sv[0]; row_arg[b * N + n] = si[0]; }
}

// ---------------- K2: serial greedy bipartite matching, one block per image ----------------
__global__ void k_greedy(const float* __restrict__ priors, const float* __restrict__ targets,
                         const float* __restrict__ row_max_in, const int* __restrict__ row_arg_in,
                         float* __restrict__ bt_score, int* __restrict__ bt_idx,
                         int P, int N) {
    int b = blockIdx.x;
    int tid = threadIdx.x;
    extern __shared__ unsigned char smem[];
    int maskWords = (P + 31) >> 5;
    unsigned int* mask = (unsigned int*)smem;
    float* truths = (float*)(mask + maskWords);  // N*4
    float* rmax = truths + (size_t)N * 4;        // N
    int* rarg = (int*)(rmax + N);                // N
    int* alive = rarg + N;                       // N
    float* redv = (float*)(alive + N);           // BS
    int* redi = (int*)(redv + BS);               // BS
    __shared__ int s_sel;

    for (int w = tid; w < maskWords; w += blockDim.x) mask[w] = 0u;
    for (int t = tid; t < N; t += blockDim.x) {
        rmax[t] = row_max_in[b * N + t];
        rarg[t] = row_arg_in[b * N + t];
        alive[t] = 1;
        truths[t * 4 + 0] = targets[(size_t)(b * N + t) * 5 + 0];
        truths[t * 4 + 1] = targets[(size_t)(b * N + t) * 5 + 1];
        truths[t * 4 + 2] = targets[(size_t)(b * N + t) * 5 + 2];
        truths[t * 4 + 3] = targets[(size_t)(b * N + t) * 5 + 3];
    }
    __syncthreads();

    for (int it = 0; it < N; it++) {
        if (tid == 0) {
            // flat argmax == (max value, then smallest row, then its cached smallest col)
            float bv = -2.f; int bj = 0;
            for (int r = 0; r < N; r++) {
                if (alive[r] && rmax[r] > bv) { bv = rmax[r]; bj = r; }
            }
            int si_ = rarg[bj];
            bt_score[(size_t)b * P + si_] = bv;
            bt_idx[(size_t)b * P + si_] = bj;
            alive[bj] = 0;
            mask[si_ >> 5] |= (1u << (si_ & 31));
            s_sel = si_;
        }
        __syncthreads();
        int sel = s_sel;
        // rescan alive rows whose cached argmax column just got masked
        for (int r = 0; r < N; r++) {
            if (!(alive[r] != 0 && rarg[r] == sel)) continue;  // uniform (shared reads)
            float tx1 = truths[r * 4 + 0], ty1 = truths[r * 4 + 1];
            float tx2 = truths[r * 4 + 2], ty2 = truths[r * 4 + 3];
            float bv = -2.f; int bi = 0x7fffffff;
            for (int i = tid; i < P; i += blockDim.x) {
                if (mask[i >> 5] & (1u << (i & 31))) continue;
                float pcx = priors[(size_t)i * 4 + 0], pcy = priors[(size_t)i * 4 + 1];
                float pw = priors[(size_t)i * 4 + 2], ph = priors[(size_t)i * 4 + 3];
                float v = iou_box(tx1, ty1, tx2, ty2,
                                  pcx - pw * 0.5f, pcy - ph * 0.5f,
                                  pcx + pw * 0.5f, pcy + ph * 0.5f);
                if (v > bv) { bv = v; bi = i; }
            }
            redv[tid] = bv; redi[tid] = bi;
            __syncthreads();
            for (int s = BS / 2; s > 0; s >>= 1) {
                if (tid < s) {
                    if (redv[tid + s] > redv[tid] ||
                        (redv[tid + s] == redv[tid] && redi[tid + s] < redi[tid])) {
                        redv[tid] = redv[tid + s]; redi[tid] = redi[tid + s];
                    }
                }
                __syncthreads();
            }
            if (tid == 0) { rmax[r] = redv[0]; rarg[r] = redi[0]; }
            __syncthreads();
        }
        __syncthreads();  // fence before next iteration's selection writes
    }
}

// ---------------- K3: per-(b,n) top-5 of thresholded c_iou (lax.top_k semantics) ----------------
__global__ void k_topk(const float* __restrict__ loc, const float* __restrict__ priors,
                       const float* __restrict__ targets,
                       const float* __restrict__ cand_v, const int* __restrict__ cand_i,
                       const int* __restrict__ cand_cnt,
                       float* __restrict__ tk_s, int* __restrict__ tk_i,
                       int P, int N, int CAP) {
    int n = blockIdx.x, b = blockIdx.y;
    int row = b * N + n;
    int tid = threadIdx.x;

    float vals[KTOP_]; int ids[KTOP_];
#pragma unroll
    for (int k = 0; k < KTOP_; k++) { vals[k] = -1.f; ids[k] = 0x7fffffff; }

    int cnt = cand_cnt[row];
    if (cnt <= CAP) {
        for (int k = tid; k < cnt; k += blockDim.x) {
            float cv = cand_v[(size_t)row * CAP + k];
            int ci = cand_i[(size_t)row * CAP + k];
#pragma unroll
            for (int q = 0; q < KTOP_; q++) {
                bool better = (cv > vals[q]) || ((cv == vals[q]) && (ci < ids[q]));
                float tv = better ? cv : vals[q]; int ti = better ? ci : ids[q];
                cv = better ? vals[q] : cv; ci = better ? ids[q] : ci;
                vals[q] = tv; ids[q] = ti;
            }
        }
    } else {
        // deterministic fallback: full rescan of this row (overflowed candidate buffer)
        float tx1 = targets[(size_t)row * 5 + 0], ty1 = targets[(size_t)row * 5 + 1];
        float tx2 = targets[(size_t)row * 5 + 2], ty2 = targets[(size_t)row * 5 + 3];
        for (int i = tid; i < P; i += blockDim.x) {
            float pcx = priors[(size_t)i * 4 + 0], pcy = priors[(size_t)i * 4 + 1];
            float pw = priors[(size_t)i * 4 + 2], ph = priors[(size_t)i * 4 + 3];
            size_t bp = (size_t)b * P + i;
            float l0 = loc[bp * 4 + 0], l1 = loc[bp * 4 + 1];
            float l2 = loc[bp * 4 + 2], l3 = loc[bp * 4 + 3];
            float dcx = pcx + l0 * VAR0_ * pw;
            float dcy = pcy + l1 * VAR0_ * ph;
            float dw = pw * expf(l2 * VAR1_);
            float dh = ph * expf(l3 * VAR1_);
            float v = iou_box(tx1, ty1, tx2, ty2,
                              dcx - dw * 0.5f, dcy - dh * 0.5f, dcx + dw * 0.5f, dcy + dh * 0.5f);
            if (v >= T2_) {
                float cv = v; int ci = i;
#pragma unroll
                for (int q = 0; q < KTOP_; q++) {
                    bool better = (cv > vals[q]) || ((cv == vals[q]) && (ci < ids[q]));
                    float tv = better ? cv : vals[q]; int ti = better ? ci : ids[q];
                    cv = better ? vals[q] : cv; ci = better ? ids[q] : ci;
                    vals[q] = tv; ids[q] = ti;
                }
            }
        }
    }

    __shared__ float mv[BS * KTOP_];
    __shared__ int mi[BS * KTOP_];
#pragma unroll
    for (int k = 0; k < KTOP_; k++) { mv[tid * KTOP_ + k] = vals[k]; mi[tid * KTOP_ + k] = ids[k]; }
    __syncthreads();
    for (int s = BS / 2; s > 0; s >>= 1) {
        if (tid < s) {
#pragma unroll
            for (int j = 0; j < KTOP_; j++) {
                float cv = mv[(tid + s) * KTOP_ + j];
                int ci = mi[(tid + s) * KTOP_ + j];
#pragma unroll
                for (int q = 0; q < KTOP_; q++) {
                    bool better = (cv > vals[q]) || ((cv == vals[q]) && (ci < ids[q]));
                    float tv = better ? cv : vals[q]; int ti = better ? ci : ids[q];
                    cv = better ? vals[q] : cv; ci = better ? ids[q] : ci;
                    vals[q] = tv; ids[q] = ti;
                }
            }
#pragma unroll
            for (int k = 0; k < KTOP_; k++) { mv[tid * KTOP_ + k] = vals[k]; mi[tid * KTOP_ + k] = ids[k]; }
        }
        __syncthreads();
    }
    if (tid == 0) {
#pragma unroll
        for (int k = 0; k < KTOP_; k++) {
            tk_s[(size_t)row * KTOP_ + k] = (vals[k] > 0.f) ? vals[k] : 0.f;
            tk_i[(size_t)row * KTOP_ + k] = (ids[k] == 0x7fffffff) ? 0 : ids[k];
        }
    }
}

// ---------------- K3b: serial assign loop, one block per image ----------------
__global__ void k_assign(const float* __restrict__ targets,
                         const float* __restrict__ tk_s, const int* __restrict__ tk_i,
                         const float* __restrict__ bt_score, const int* __restrict__ bt_idx,
                         int* __restrict__ cb_idx, float* __restrict__ c_score,
                         int P, int N) {
    int b = blockIdx.x;
    if (threadIdx.x != 0) return;
    for (int t = 0; t < N * KTOP_; t++) {
        int i = t / KTOP_, j = t % KTOP_;
        int p = tk_i[(size_t)(b * N + i) * KTOP_ + j];
        float s = tk_s[(size_t)(b * N + i) * KTOP_ + j];
        size_t bp = (size_t)b * P + p;
        float bs = bt_score[bp];
        float conf1 = (bs < T1_) ? 0.f : targets[(size_t)(b * N + bt_idx[bp]) * 5 + 4];
        if (conf1 < 1.f && s > 0.f) { cb_idx[bp] = i; c_score[bp] = s; }
    }
}

// ---------------- K4: per-element losses + block partial sums ----------------
__global__ void k_loss(const float* __restrict__ loc, const float* __restrict__ conf,
                       const float* __restrict__ priors, const float* __restrict__ targets,
                       const float* __restrict__ bt_score, const int* __restrict__ bt_idx,
                       const float* __restrict__ cb_score, const int* __restrict__ cb_idx,
                       const float* __restrict__ c_score,
                       double* __restrict__ partials,
                       int P, int N, int C) {
    int b = blockIdx.y;
    int i = blockIdx.x * blockDim.x + threadIdx.x;
    double l1 = 0.0, l2 = 0.0, f1 = 0.0, f2 = 0.0;
    int n1 = 0, n2 = 0;
    if (i < P) {
        size_t bp = (size_t)b * P + i;
        float bs = bt_score[bp]; int bj = bt_idx[bp];
        float cbs = cb_score[bp]; int cj = cb_idx[bp]; float cs = c_score[bp];
        float lab1 = targets[(size_t)(b * N + bj) * 5 + 4];
        float conf1 = (bs < T1_) ? 0.f : lab1;
        if ((bs < T1_) && (cbs >= T2_) && (cs < T2_)) conf1 = -1.f;
        float lab2 = targets[(size_t)(b * N + cj) * 5 + 4];
        float conf2 = (cs < T2_) ? -1.f : lab2;
        bool m1 = conf1 > 0.f, m2 = conf2 > 0.f;
        n1 = m1 ? 1 : 0; n2 = m2 ? 1 : 0;

        float pcx = priors[(size_t)i * 4 + 0], pcy = priors[(size_t)i * 4 + 1];
        float pw = priors[(size_t)i * 4 + 2], ph = priors[(size_t)i * 4 + 3];
        float p0 = loc[bp * 4 + 0], p1 = loc[bp * 4 + 1], p2 = loc[bp * 4 + 2], p3 = loc[bp * 4 + 3];

        if (m1) {
            const float* tb = &targets[(size_t)(b * N + bj) * 5];
            float gx = ((tb[0] + tb[2]) * 0.5f - pcx) / (VAR0_ * pw);
            float gy = ((tb[1] + tb[3]) * 0.5f - pcy) / (VAR0_ * ph);
            float gw = logf((tb[2] - tb[0]) / pw) / VAR1_;
            float gh = logf((tb[3] - tb[1]) / ph) / VAR1_;
            l1 = (double)(sl1(p0 - gx) + sl1(p1 - gy) + sl1(p2 - gw) + sl1(p3 - gh));
        }
        if (m2) {
            const float* tb = &targets[(size_t)(b * N + cj) * 5];
            float gx = ((tb[0] + tb[2]) * 0.5f - pcx) / (VAR0_ * pw);
            float gy = ((tb[1] + tb[3]) * 0.5f - pcy) / (VAR0_ * ph);
            float gw = logf((tb[2] - tb[0]) / pw) / VAR1_;
            float gh = logf((tb[3] - tb[1]) / ph) / VAR1_;
            l2 = (double)(sl1(p0 - gx) + sl1(p1 - gy) + sl1(p2 - gw) + sl1(p3 - gh));
        }
        {   // focal 1
            float t = fmaxf(conf1, 0.f);
            float keep = (conf1 >= 0.f) ? 1.f : 0.f;
            int cls = (int)t;
            float x = conf[bp * C + cls];
            float ce = fmaxf(x, 0.f) - x * t + log1pf(expf(-fabsf(x)));
            float a = t * ALPHA_ + (1.f - t) * (1.f - ALPHA_);
            float pr = 1.f / (1.f + expf(-x));
            float pt = (t == 1.f) ? pr : (1.f - pr);
            float om = 1.f - pt;
            f1 = (double)(a * om * om * ce * keep);
        }
        {   // focal 2 (iou-weighted)
            float t = fmaxf(conf2, 0.f);
            float keep = (conf2 >= 0.f) ? 1.f : 0.f;
            int cls = (int)t;
            float x = conf[bp * C + cls];
            float ce = fmaxf(x, 0.f) - x * t + log1pf(expf(-fabsf(x)));
            float a = cs * (t * ALPHA_ + (1.f - t) * (1.f - ALPHA_));
            float pr = 1.f / (1.f + expf(-x));
            float pt = (t == 1.f) ? pr : (1.f - pr);
            float om = 1.f - pt;
            f2 = (double)(a * om * om * ce * keep);
        }
    }
    __shared__ double sd[BS * 4];
    __shared__ int sn[BS * 2];
    int tid = threadIdx.x;
    sd[tid * 4 + 0] = l1; sd[tid * 4 + 1] = l2; sd[tid * 4 + 2] = f1; sd[tid * 4 + 3] = f2;
    sn[tid * 2 + 0] = n1; sn[tid * 2 + 1] = n2;
    __syncthreads();
    for (int s = BS / 2; s > 0; s >>= 1) {
        if (tid < s) {
            sd[tid * 4 + 0] += sd[(tid + s) * 4 + 0];
            sd[tid * 4 + 1] += sd[(tid + s) * 4 + 1];
            sd[tid * 4 + 2] += sd[(tid + s) * 4 + 2];
            sd[tid * 4 + 3] += sd[(tid + s) * 4 + 3];
            sn[tid * 2 + 0] += sn[(tid + s) * 2 + 0];
            sn[tid * 2 + 1] += sn[(tid + s) * 2 + 1];
        }
        __syncthreads();
    }
    if (tid == 0) {
        int blk = blockIdx.y * gridDim.x + blockIdx.x;
        partials[(size_t)blk * 6 + 0] = sd[0];
        partials[(size_t)blk * 6 + 1] = sd[1];
        partials[(size_t)blk * 6 + 2] = sd[2];
        partials[(size_t)blk * 6 + 3] = sd[3];
        partials[(size_t)blk * 6 + 4] = (double)sn[0];
        partials[(size_t)blk * 6 + 5] = (double)sn[1];
    }
}

// ---------------- K5: final reduction + loss assembly ----------------
__global__ void k_final(const double* __restrict__ partials, int nPart, float* __restrict__ out) {
    int tid = threadIdx.x;
    double a[6] = {0, 0, 0, 0, 0, 0};
    for (int k = tid; k < nPart; k += BS) {
#pragma unroll
        for (int j = 0; j < 6; j++) a[j] += partials[(size_t)k * 6 + j];
    }
    __shared__ double sd[BS * 6];
#pragma unroll
    for (int j = 0; j < 6; j++) sd[tid * 6 + j] = a[j];
    __syncthreads();
    for (int s = BS / 2; s > 0; s >>= 1) {
        if (tid < s) {
#pragma unroll
            for (int j = 0; j < 6; j++) sd[tid * 6 + j] += sd[(tid + s) * 6 + j];
        }
        __syncthreads();
    }
    if (tid == 0) {
        double L1 = sd[0], L2 = sd[1], F1 = sd[2], F2 = sd[3], N1 = sd[4], N2 = sd[5];
        double l1v = L1 / fmax(N1, 1.0), l2v = L2 / fmax(N2, 1.0);
        double f1v = F1 / fmax(N1, 1.0), f2v = F2 / fmax(N2, 1.0);
        double locl = (N1 > 0 ? l1v : 0.0) + (N2 > 0 ? l2v : 0.0);
        double clsl = (N1 > 0 ? f1v : 0.0) + (N2 > 0 ? f2v : 0.0);
        if (N1 == 0 && N2 == 0) { locl = 1e-4; clsl = 1e-4; }
        out[0] = (float)locl;
        out[1] = (float)clsl;
    }
}

extern "C" void kernel_launch(void* const* d_in, const int* in_sizes, int n_in,
                              void* d_out, int out_size, void* d_ws, size_t ws_size,
                              hipStream_t stream) {
    const float* loc = (const float*)d_in[0];
    const float* conf = (const float*)d_in[1];
    const float* priors = (const float*)d_in[2];
    const float* targets = (const float*)d_in[3];

    int P = in_sizes[2] / 4;
    int B = in_sizes[0] / (P * 4);
    int N = in_sizes[3] / (B * 5);
    int C = in_sizes[1] / (B * P);
    const int CAP = 2048;
    size_t BP = (size_t)B * P;

    unsigned char* ws = (unsigned char*)d_ws;
    size_t off = 0;
    auto alloc = [&](size_t bytes) { size_t cur = off; off += (bytes + 255) & ~(size_t)255; return cur; };
    float* bt_score = (float*)(ws + alloc(BP * 4));
    int* bt_idx = (int*)(ws + alloc(BP * 4));
    float* cb_score = (float*)(ws + alloc(BP * 4));
    int* cb_idx = (int*)(ws + alloc(BP * 4));
    float* c_score = (float*)(ws + alloc(BP * 4));
    float* row_max = (float*)(ws + alloc((size_t)B * N * 4));
    int* row_arg = (int*)(ws + alloc((size_t)B * N * 4));
    float* tk_s = (float*)(ws + alloc((size_t)B * N * KTOP_ * 4));
    int* tk_i = (int*)(ws + alloc((size_t)B * N * KTOP_ * 4));
    float* cand_v = (float*)(ws + alloc((size_t)B * N * CAP * 4));
    int* cand_i = (int*)(ws + alloc((size_t)B * N * CAP * 4));
    int* cand_cnt = (int*)(ws + alloc((size_t)B * N * 4));
    int bx = (P + BS - 1) / BS;
    double* partials = (double*)(ws + alloc((size_t)bx * B * 6 * 8));
    float* out = (float*)d_out;

    k_zero<<<dim3((B * N + BS - 1) / BS), dim3(BS), 0, stream>>>(cand_cnt, B * N);
    dim3 g1(bx, B);
    k_per_prior<<<g1, BS, 0, stream>>>(loc, priors, targets, bt_score, bt_idx,
                                       cb_score, cb_idx, c_score,
                                       cand_v, cand_i, cand_cnt, P, N, CAP);
    k_row_max<<<dim3(N, B), BS, 0, stream>>>(priors, targets, row_max, row_arg, P, N);
    int maskWords = (P + 31) / 32;
    size_t shmem = (size_t)maskWords * 4 + (size_t)N * 16 + (size_t)N * 12 + BS * 8 + 64;
    k_greedy<<<dim3(B), BS, shmem, stream>>>(priors, targets, row_max, row_arg,
                                             bt_score, bt_idx, P, N);
    k_topk<<<dim3(N, B), BS, 0, stream>>>(loc, priors, targets, cand_v, cand_i, cand_cnt,
                                          tk_s, tk_i, P, N, CAP);
    k_assign<<<dim3(B), 64, 0, stream>>>(targets, tk_s, tk_i, bt_score, bt_idx,
                                         cb_idx, c_score, P, N);
    k_loss<<<g1, BS, 0, stream>>>(loc, conf, priors, targets, bt_score, bt_idx,
                                  cb_score, cb_idx, c_score, partials, P, N, C);
    k_final<<<1, BS, 0, stream>>>(partials, bx * B, out);
}

// Round 2
// 374.163 us; speedup vs baseline: 1.5656x; 1.5656x over previous
//
#include <hip/hip_runtime.h>
#include <cstdint>
#include <cstddef>

#define VAR0_ 0.1f
#define VAR1_ 0.2f
#define KTOP_ 5
#define T1_ 0.35f
#define T2_ 0.5f
#define ALPHA_ 0.25f
#define BETA_ 0.11f
#define BS 256

__device__ __forceinline__ float iou_box(float ax1, float ay1, float ax2, float ay2,
                                         float bx1, float by1, float bx2, float by2) {
    float lx = fmaxf(ax1, bx1), ly = fmaxf(ay1, by1);
    float rx = fminf(ax2, bx2), ry = fminf(ay2, by2);
    float w = fmaxf(rx - lx, 0.f), h = fmaxf(ry - ly, 0.f);
    float inter = w * h;
    float aa = (ax2 - ax1) * (ay2 - ay1);
    float ab = (bx2 - bx1) * (by2 - by1);
    return inter / (aa + ab - inter);
}

__device__ __forceinline__ float sl1(float d) {
    float x = fabsf(d);
    return (x >= BETA_) ? (x - 0.5f * BETA_) : (0.5f * x * x / BETA_);
}

// ---------------- K0: zero candidate counters ----------------
__global__ void k_zero(int* __restrict__ cand_cnt, int n) {
    int i = blockIdx.x * blockDim.x + threadIdx.x;
    if (i < n) cand_cnt[i] = 0;
}

// ---------------- K1: per-prior column maxes + decode + candidate harvest ----------------
__global__ void k_per_prior(const float4* __restrict__ loc4, const float4* __restrict__ priors4,
                            const float* __restrict__ targets,
                            float* __restrict__ bt_score, int* __restrict__ bt_idx,
                            float* __restrict__ cb_score, int* __restrict__ cb_idx,
                            float* __restrict__ c_score,
                            float* __restrict__ cand_v, int* __restrict__ cand_i,
                            int* __restrict__ cand_cnt,
                            int P, int N, int CAP) {
    int b = blockIdx.y;
    int i = blockIdx.x * blockDim.x + threadIdx.x;
    __shared__ float tr[64 * 4];
    for (int t = threadIdx.x; t < N; t += blockDim.x) {
        tr[t * 4 + 0] = targets[(size_t)(b * N + t) * 5 + 0];
        tr[t * 4 + 1] = targets[(size_t)(b * N + t) * 5 + 1];
        tr[t * 4 + 2] = targets[(size_t)(b * N + t) * 5 + 2];
        tr[t * 4 + 3] = targets[(size_t)(b * N + t) * 5 + 3];
    }
    __syncthreads();
    if (i >= P) return;

    float4 pr = priors4[i];
    float pcx = pr.x, pcy = pr.y, pw = pr.z, ph = pr.w;
    float px1 = pcx - pw * 0.5f, py1 = pcy - ph * 0.5f;
    float px2 = pcx + pw * 0.5f, py2 = pcy + ph * 0.5f;

    // stage-1: max over truths of IoU(truth, prior_pt); first-max tiebreak
    float bv = -1.f; int bn = 0;
    for (int n = 0; n < N; n++) {
        float v = iou_box(tr[n * 4 + 0], tr[n * 4 + 1], tr[n * 4 + 2], tr[n * 4 + 3],
                          px1, py1, px2, py2);
        if (v > bv) { bv = v; bn = n; }
    }

    // decode(loc, prior)
    size_t bp = (size_t)b * P + i;
    float4 lc = loc4[bp];
    float dcx = pcx + lc.x * VAR0_ * pw;
    float dcy = pcy + lc.y * VAR0_ * ph;
    float dw = pw * expf(lc.z * VAR1_);
    float dh = ph * expf(lc.w * VAR1_);
    float dx1 = dcx - dw * 0.5f, dy1 = dcy - dh * 0.5f;
    float dx2 = dcx + dw * 0.5f, dy2 = dcy + dh * 0.5f;

    // stage-2: max over truths of IoU(truth, decoded); harvest candidates >= T2
    float cv = -1.f; int cn = 0;
    for (int n = 0; n < N; n++) {
        float v = iou_box(tr[n * 4 + 0], tr[n * 4 + 1], tr[n * 4 + 2], tr[n * 4 + 3],
                          dx1, dy1, dx2, dy2);
        if (v > cv) { cv = v; cn = n; }
        if (v >= T2_) {
            int pos = atomicAdd(&cand_cnt[b * N + n], 1);
            if (pos < CAP) {
                size_t o = (size_t)(b * N + n) * CAP + pos;
                cand_v[o] = v; cand_i[o] = i;
            }
        }
    }
    bt_score[bp] = bv; bt_idx[bp] = bn;
    cb_score[bp] = cv; cb_idx[bp] = cn;
    c_score[bp] = 0.f;
}

// ---------------- K1b: per-(b,n) row max/argmax over all priors ----------------
__global__ void k_row_max(const float4* __restrict__ priors4, const float* __restrict__ targets,
                          float* __restrict__ row_max, int* __restrict__ row_arg,
                          int P, int N) {
    int n = blockIdx.x, b = blockIdx.y;
    float tx1 = targets[(size_t)(b * N + n) * 5 + 0];
    float ty1 = targets[(size_t)(b * N + n) * 5 + 1];
    float tx2 = targets[(size_t)(b * N + n) * 5 + 2];
    float ty2 = targets[(size_t)(b * N + n) * 5 + 3];
    float bv = -1.f; int bi = 0x7fffffff;
    for (int i = threadIdx.x; i < P; i += blockDim.x) {
        float4 pr = priors4[i];
        float v = iou_box(tx1, ty1, tx2, ty2,
                          pr.x - pr.z * 0.5f, pr.y - pr.w * 0.5f,
                          pr.x + pr.z * 0.5f, pr.y + pr.w * 0.5f);
        if (v > bv) { bv = v; bi = i; }
    }
    __shared__ float sv[BS];
    __shared__ int si[BS];
    int tid = threadIdx.x;
    sv[tid] = bv; si[tid] = bi;
    __syncthreads();
    for (int s = BS / 2; s > 0; s >>= 1) {
        if (tid < s) {
            if (sv[tid + s] > sv[tid] || (sv[tid + s] == sv[tid] && si[tid + s] < si[tid])) {
                sv[tid] = sv[tid + s]; si[tid] = si[tid + s];
            }
        }
        __syncthreads();
    }
    if (tid == 0) { row_max[b * N + n] = sv[0]; row_arg[b * N + n] = si[0]; }
}

// ---------------- K2: greedy bipartite matching — ONE WAVE per image, register rows ----------------
__global__ void k_greedy(const float4* __restrict__ priors4, const float* __restrict__ targets,
                         const float* __restrict__ row_max_in, const int* __restrict__ row_arg_in,
                         float* __restrict__ bt_score, int* __restrict__ bt_idx,
                         int P, int N) {
    int b = blockIdx.x;
    int lane = threadIdx.x;  // block == 1 wave of 64
    extern __shared__ unsigned int mask[];
    int maskWords = (P + 31) >> 5;
    for (int w = lane; w < maskWords; w += 64) mask[w] = 0u;

    // lane r (< N) owns row r in registers
    float rmax = -2.f; int rarg = 0x7fffffff; int alive = 0;
    float tx1 = 0.f, ty1 = 0.f, tx2 = 0.f, ty2 = 0.f;
    if (lane < N) {
        rmax = row_max_in[b * N + lane];
        rarg = row_arg_in[b * N + lane];
        alive = 1;
        tx1 = targets[(size_t)(b * N + lane) * 5 + 0];
        ty1 = targets[(size_t)(b * N + lane) * 5 + 1];
        tx2 = targets[(size_t)(b * N + lane) * 5 + 2];
        ty2 = targets[(size_t)(b * N + lane) * 5 + 3];
    }
    __syncthreads();

    for (int it = 0; it < N; it++) {
        // wave argmax over alive rows: (value desc, row asc)
        float v = (lane < N && alive) ? rmax : -3.f;
        int idx = lane;
#pragma unroll
        for (int off = 32; off > 0; off >>= 1) {
            float ov = __shfl_xor(v, off);
            int oi = __shfl_xor(idx, off);
            if (ov > v || (ov == v && oi < idx)) { v = ov; idx = oi; }
        }
        int bj = idx;
        float bv = v;
        int sel = __shfl(rarg, bj);
        if (lane == bj) alive = 0;
        if (lane == 0) {
            bt_score[(size_t)b * P + sel] = bv;
            bt_idx[(size_t)b * P + sel] = bj;
            mask[sel >> 5] |= (1u << (sel & 31));
        }
        __syncthreads();  // mask write visible to wave

        // rescan rows whose cached argmax column just got masked (rare)
        unsigned long long coll = __ballot(lane < N && alive && rarg == sel);
        while (coll) {
            int r = __ffsll((long long)coll) - 1;
            coll &= coll - 1;
            float rx1 = __shfl(tx1, r), ry1 = __shfl(ty1, r);
            float rx2 = __shfl(tx2, r), ry2 = __shfl(ty2, r);
            float nv = -2.f; int ni = 0x7fffffff;
            for (int i = lane; i < P; i += 64) {
                if (mask[i >> 5] & (1u << (i & 31))) continue;
                float4 pr = priors4[i];
                float vv = iou_box(rx1, ry1, rx2, ry2,
                                   pr.x - pr.z * 0.5f, pr.y - pr.w * 0.5f,
                                   pr.x + pr.z * 0.5f, pr.y + pr.w * 0.5f);
                if (vv > nv) { nv = vv; ni = i; }  // strided i increasing -> smallest idx kept
            }
#pragma unroll
            for (int off = 32; off > 0; off >>= 1) {
                float ov = __shfl_xor(nv, off);
                int oi = __shfl_xor(ni, off);
                if (ov > nv || (ov == nv && oi < ni)) { nv = ov; ni = oi; }
            }
            if (lane == r) { rmax = nv; rarg = ni; }
        }
        __syncthreads();
    }
}

// ---------------- K3: per-(b,n) top-5 of thresholded c_iou (lax.top_k semantics) ----------------
__global__ void k_topk(const float4* __restrict__ loc4, const float4* __restrict__ priors4,
                       const float* __restrict__ targets,
                       const float* __restrict__ cand_v, const int* __restrict__ cand_i,
                       const int* __restrict__ cand_cnt,
                       float* __restrict__ tk_s, int* __restrict__ tk_i,
                       int P, int N, int CAP) {
    int n = blockIdx.x, b = blockIdx.y;
    int row = b * N + n;
    int tid = threadIdx.x;

    float vals[KTOP_]; int ids[KTOP_];
#pragma unroll
    for (int k = 0; k < KTOP_; k++) { vals[k] = -1.f; ids[k] = 0x7fffffff; }

    int cnt = cand_cnt[row];
    if (cnt <= CAP) {
        for (int k = tid; k < cnt; k += blockDim.x) {
            float cv = cand_v[(size_t)row * CAP + k];
            int ci = cand_i[(size_t)row * CAP + k];
#pragma unroll
            for (int q = 0; q < KTOP_; q++) {
                bool better = (cv > vals[q]) || ((cv == vals[q]) && (ci < ids[q]));
                float tv = better ? cv : vals[q]; int ti = better ? ci : ids[q];
                cv = better ? vals[q] : cv; ci = better ? ids[q] : ci;
                vals[q] = tv; ids[q] = ti;
            }
        }
    } else {
        // deterministic fallback: full rescan of this row (overflowed candidate buffer)
        float tx1 = targets[(size_t)row * 5 + 0], ty1 = targets[(size_t)row * 5 + 1];
        float tx2 = targets[(size_t)row * 5 + 2], ty2 = targets[(size_t)row * 5 + 3];
        for (int i = tid; i < P; i += blockDim.x) {
            float4 pr = priors4[i];
            size_t bp = (size_t)b * P + i;
            float4 lc = loc4[bp];
            float dcx = pr.x + lc.x * VAR0_ * pr.z;
            float dcy = pr.y + lc.y * VAR0_ * pr.w;
            float dw = pr.z * expf(lc.z * VAR1_);
            float dh = pr.w * expf(lc.w * VAR1_);
            float v = iou_box(tx1, ty1, tx2, ty2,
                              dcx - dw * 0.5f, dcy - dh * 0.5f, dcx + dw * 0.5f, dcy + dh * 0.5f);
            if (v >= T2_) {
                float cv = v; int ci = i;
#pragma unroll
                for (int q = 0; q < KTOP_; q++) {
                    bool better = (cv > vals[q]) || ((cv == vals[q]) && (ci < ids[q]));
                    float tv = better ? cv : vals[q]; int ti = better ? ci : ids[q];
                    cv = better ? vals[q] : cv; ci = better ? ids[q] : ci;
                    vals[q] = tv; ids[q] = ti;
                }
            }
        }
    }

    __shared__ float mv[BS * KTOP_];
    __shared__ int mi[BS * KTOP_];
#pragma unroll
    for (int k = 0; k < KTOP_; k++) { mv[tid * KTOP_ + k] = vals[k]; mi[tid * KTOP_ + k] = ids[k]; }
    __syncthreads();
    for (int s = BS / 2; s > 0; s >>= 1) {
        if (tid < s) {
#pragma unroll
            for (int j = 0; j < KTOP_; j++) {
                float cv = mv[(tid + s) * KTOP_ + j];
                int ci = mi[(tid + s) * KTOP_ + j];
#pragma unroll
                for (int q = 0; q < KTOP_; q++) {
                    bool better = (cv > vals[q]) || ((cv == vals[q]) && (ci < ids[q]));
                    float tv = better ? cv : vals[q]; int ti = better ? ci : ids[q];
                    cv = better ? vals[q] : cv; ci = better ? ids[q] : ci;
                    vals[q] = tv; ids[q] = ti;
                }
            }
#pragma unroll
            for (int k = 0; k < KTOP_; k++) { mv[tid * KTOP_ + k] = vals[k]; mi[tid * KTOP_ + k] = ids[k]; }
        }
        __syncthreads();
    }
    if (tid == 0) {
#pragma unroll
        for (int k = 0; k < KTOP_; k++) {
            tk_s[(size_t)row * KTOP_ + k] = (vals[k] > 0.f) ? vals[k] : 0.f;
            tk_i[(size_t)row * KTOP_ + k] = (ids[k] == 0x7fffffff) ? 0 : ids[k];
        }
    }
}

// ---------------- K3b: assign loop, parallel last-writer-wins ----------------
__global__ void k_assign(const float* __restrict__ targets,
                         const float* __restrict__ tk_s, const int* __restrict__ tk_i,
                         const float* __restrict__ bt_score, const int* __restrict__ bt_idx,
                         int* __restrict__ cb_idx, float* __restrict__ c_score,
                         int P, int N) {
    int b = blockIdx.x;
    int tid = threadIdx.x;
    int T = N * KTOP_;  // 160
    __shared__ int sh_p[512];
    __shared__ float sh_s[512];
    __shared__ int sh_c[512];
    if (tid < T) {
        int i = tid / KTOP_, j = tid % KTOP_;
        int p = tk_i[(size_t)(b * N + i) * KTOP_ + j];
        float s = tk_s[(size_t)(b * N + i) * KTOP_ + j];
        size_t bp = (size_t)b * P + p;
        float bs = bt_score[bp];
        float conf1 = (bs < T1_) ? 0.f : targets[(size_t)(b * N + bt_idx[bp]) * 5 + 4];
        sh_p[tid] = p; sh_s[tid] = s;
        sh_c[tid] = (conf1 < 1.f && s > 0.f) ? 1 : 0;
    }
    __syncthreads();
    if (tid < T && sh_c[tid]) {
        int p = sh_p[tid];
        bool last = true;
        for (int t2 = tid + 1; t2 < T; t2++) {
            if (sh_c[t2] && sh_p[t2] == p) { last = false; break; }
        }
        if (last) {
            size_t bp = (size_t)b * P + p;
            cb_idx[bp] = tid / KTOP_;
            c_score[bp] = sh_s[tid];
        }
    }
}

// ---------------- K4: per-element losses + block partial sums ----------------
__global__ void k_loss(const float4* __restrict__ loc4, const float* __restrict__ conf,
                       const float4* __restrict__ priors4, const float* __restrict__ targets,
                       const float* __restrict__ bt_score, const int* __restrict__ bt_idx,
                       const float* __restrict__ cb_score, const int* __restrict__ cb_idx,
                       const float* __restrict__ c_score,
                       double* __restrict__ partials,
                       int P, int N, int C) {
    int b = blockIdx.y;
    int i = blockIdx.x * blockDim.x + threadIdx.x;
    double l1 = 0.0, l2 = 0.0, f1 = 0.0, f2 = 0.0;
    int n1 = 0, n2 = 0;
    if (i < P) {
        size_t bp = (size_t)b * P + i;
        float bs = bt_score[bp]; int bj = bt_idx[bp];
        float cbs = cb_score[bp]; int cj = cb_idx[bp]; float cs = c_score[bp];
        float lab1 = targets[(size_t)(b * N + bj) * 5 + 4];
        float conf1 = (bs < T1_) ? 0.f : lab1;
        if ((bs < T1_) && (cbs >= T2_) && (cs < T2_)) conf1 = -1.f;
        float lab2 = targets[(size_t)(b * N + cj) * 5 + 4];
        float conf2 = (cs < T2_) ? -1.f : lab2;
        bool m1 = conf1 > 0.f, m2 = conf2 > 0.f;
        n1 = m1 ? 1 : 0; n2 = m2 ? 1 : 0;

        float4 pr = priors4[i];
        float pcx = pr.x, pcy = pr.y, pw = pr.z, ph = pr.w;
        float4 lc = loc4[bp];
        float p0 = lc.x, p1 = lc.y, p2 = lc.z, p3 = lc.w;

        if (m1) {
            const float* tb = &targets[(size_t)(b * N + bj) * 5];
            float gx = ((tb[0] + tb[2]) * 0.5f - pcx) / (VAR0_ * pw);
            float gy = ((tb[1] + tb[3]) * 0.5f - pcy) / (VAR0_ * ph);
            float gw = logf((tb[2] - tb[0]) / pw) / VAR1_;
            float gh = logf((tb[3] - tb[1]) / ph) / VAR1_;
            l1 = (double)(sl1(p0 - gx) + sl1(p1 - gy) + sl1(p2 - gw) + sl1(p3 - gh));
        }
        if (m2) {
            const float* tb = &targets[(size_t)(b * N + cj) * 5];
            float gx = ((tb[0] + tb[2]) * 0.5f - pcx) / (VAR0_ * pw);
            float gy = ((tb[1] + tb[3]) * 0.5f - pcy) / (VAR0_ * ph);
            float gw = logf((tb[2] - tb[0]) / pw) / VAR1_;
            float gh = logf((tb[3] - tb[1]) / ph) / VAR1_;
            l2 = (double)(sl1(p0 - gx) + sl1(p1 - gy) + sl1(p2 - gw) + sl1(p3 - gh));
        }
        {   // focal 1
            float t = fmaxf(conf1, 0.f);
            float keep = (conf1 >= 0.f) ? 1.f : 0.f;
            int cls = (int)t;
            float x = conf[bp * C + cls];
            float ce = fmaxf(x, 0.f) - x * t + log1pf(expf(-fabsf(x)));
            float a = t * ALPHA_ + (1.f - t) * (1.f - ALPHA_);
            float pr_ = 1.f / (1.f + expf(-x));
            float pt = (t == 1.f) ? pr_ : (1.f - pr_);
            float om = 1.f - pt;
            f1 = (double)(a * om * om * ce * keep);
        }
        {   // focal 2 (iou-weighted)
            float t = fmaxf(conf2, 0.f);
            float keep = (conf2 >= 0.f) ? 1.f : 0.f;
            int cls = (int)t;
            float x = conf[bp * C + cls];
            float ce = fmaxf(x, 0.f) - x * t + log1pf(expf(-fabsf(x)));
            float a = cs * (t * ALPHA_ + (1.f - t) * (1.f - ALPHA_));
            float pr_ = 1.f / (1.f + expf(-x));
            float pt = (t == 1.f) ? pr_ : (1.f - pr_);
            float om = 1.f - pt;
            f2 = (double)(a * om * om * ce * keep);
        }
    }
    __shared__ double sd[BS * 4];
    __shared__ int sn[BS * 2];
    int tid = threadIdx.x;
    sd[tid * 4 + 0] = l1; sd[tid * 4 + 1] = l2; sd[tid * 4 + 2] = f1; sd[tid * 4 + 3] = f2;
    sn[tid * 2 + 0] = n1; sn[tid * 2 + 1] = n2;
    __syncthreads();
    for (int s = BS / 2; s > 0; s >>= 1) {
        if (tid < s) {
            sd[tid * 4 + 0] += sd[(tid + s) * 4 + 0];
            sd[tid * 4 + 1] += sd[(tid + s) * 4 + 1];
            sd[tid * 4 + 2] += sd[(tid + s) * 4 + 2];
            sd[tid * 4 + 3] += sd[(tid + s) * 4 + 3];
            sn[tid * 2 + 0] += sn[(tid + s) * 2 + 0];
            sn[tid * 2 + 1] += sn[(tid + s) * 2 + 1];
        }
        __syncthreads();
    }
    if (tid == 0) {
        int blk = blockIdx.y * gridDim.x + blockIdx.x;
        partials[(size_t)blk * 6 + 0] = sd[0];
        partials[(size_t)blk * 6 + 1] = sd[1];
        partials[(size_t)blk * 6 + 2] = sd[2];
        partials[(size_t)blk * 6 + 3] = sd[3];
        partials[(size_t)blk * 6 + 4] = (double)sn[0];
        partials[(size_t)blk * 6 + 5] = (double)sn[1];
    }
}

// ---------------- K5: final reduction + loss assembly ----------------
__global__ void k_final(const double* __restrict__ partials, int nPart, float* __restrict__ out) {
    int tid = threadIdx.x;
    double a[6] = {0, 0, 0, 0, 0, 0};
    for (int k = tid; k < nPart; k += BS) {
#pragma unroll
        for (int j = 0; j < 6; j++) a[j] += partials[(size_t)k * 6 + j];
    }
    __shared__ double sd[BS * 6];
#pragma unroll
    for (int j = 0; j < 6; j++) sd[tid * 6 + j] = a[j];
    __syncthreads();
    for (int s = BS / 2; s > 0; s >>= 1) {
        if (tid < s) {
#pragma unroll
            for (int j = 0; j < 6; j++) sd[tid * 6 + j] += sd[(tid + s) * 6 + j];
        }
        __syncthreads();
    }
    if (tid == 0) {
        double L1 = sd[0], L2 = sd[1], F1 = sd[2], F2 = sd[3], N1 = sd[4], N2 = sd[5];
        double l1v = L1 / fmax(N1, 1.0), l2v = L2 / fmax(N2, 1.0);
        double f1v = F1 / fmax(N1, 1.0), f2v = F2 / fmax(N2, 1.0);
        double locl = (N1 > 0 ? l1v : 0.0) + (N2 > 0 ? l2v : 0.0);
        double clsl = (N1 > 0 ? f1v : 0.0) + (N2 > 0 ? f2v : 0.0);
        if (N1 == 0 && N2 == 0) { locl = 1e-4; clsl = 1e-4; }
        out[0] = (float)locl;
        out[1] = (float)clsl;
    }
}

extern "C" void kernel_launch(void* const* d_in, const int* in_sizes, int n_in,
                              void* d_out, int out_size, void* d_ws, size_t ws_size,
                              hipStream_t stream) {
    const float* loc = (const float*)d_in[0];
    const float* conf = (const float*)d_in[1];
    const float* priors = (const float*)d_in[2];
    const float* targets = (const float*)d_in[3];
    const float4* loc4 = (const float4*)d_in[0];
    const float4* priors4 = (const float4*)d_in[2];

    int P = in_sizes[2] / 4;
    int B = in_sizes[0] / (P * 4);
    int N = in_sizes[3] / (B * 5);
    int C = in_sizes[1] / (B * P);
    const int CAP = 2048;
    size_t BP = (size_t)B * P;

    unsigned char* ws = (unsigned char*)d_ws;
    size_t off = 0;
    auto alloc = [&](size_t bytes) { size_t cur = off; off += (bytes + 255) & ~(size_t)255; return cur; };
    float* bt_score = (float*)(ws + alloc(BP * 4));
    int* bt_idx = (int*)(ws + alloc(BP * 4));
    float* cb_score = (float*)(ws + alloc(BP * 4));
    int* cb_idx = (int*)(ws + alloc(BP * 4));
    float* c_score = (float*)(ws + alloc(BP * 4));
    float* row_max = (float*)(ws + alloc((size_t)B * N * 4));
    int* row_arg = (int*)(ws + alloc((size_t)B * N * 4));
    float* tk_s = (float*)(ws + alloc((size_t)B * N * KTOP_ * 4));
    int* tk_i = (int*)(ws + alloc((size_t)B * N * KTOP_ * 4));
    float* cand_v = (float*)(ws + alloc((size_t)B * N * CAP * 4));
    int* cand_i = (int*)(ws + alloc((size_t)B * N * CAP * 4));
    int* cand_cnt = (int*)(ws + alloc((size_t)B * N * 4));
    int bx = (P + BS - 1) / BS;
    double* partials = (double*)(ws + alloc((size_t)bx * B * 6 * 8));
    float* out = (float*)d_out;

    k_zero<<<dim3((B * N + BS - 1) / BS), dim3(BS), 0, stream>>>(cand_cnt, B * N);
    dim3 g1(bx, B);
    k_per_prior<<<g1, BS, 0, stream>>>(loc4, priors4, targets, bt_score, bt_idx,
                                       cb_score, cb_idx, c_score,
                                       cand_v, cand_i, cand_cnt, P, N, CAP);
    k_row_max<<<dim3(N, B), BS, 0, stream>>>(priors4, targets, row_max, row_arg, P, N);
    int maskWords = (P + 31) / 32;
    size_t shmem = (size_t)maskWords * 4;
    k_greedy<<<dim3(B), 64, shmem, stream>>>(priors4, targets, row_max, row_arg,
                                             bt_score, bt_idx, P, N);
    k_topk<<<dim3(N, B), BS, 0, stream>>>(loc4, priors4, targets, cand_v, cand_i, cand_cnt,
                                          tk_s, tk_i, P, N, CAP);
    k_assign<<<dim3(B), BS, 0, stream>>>(targets, tk_s, tk_i, bt_score, bt_idx,
                                         cb_idx, c_score, P, N);
    k_loss<<<g1, BS, 0, stream>>>(loc4, conf, priors4, targets, bt_score, bt_idx,
                                  cb_score, cb_idx, c_score, partials, P, N, C);
    k_final<<<1, BS, 0, stream>>>(partials, bx * B, out);
}

// Round 3
// 357.162 us; speedup vs baseline: 1.6401x; 1.0476x over previous
//
#include <hip/hip_runtime.h>
#include <cstdint>
#include <cstddef>

#define VAR0_ 0.1f
#define VAR1_ 0.2f
#define KTOP_ 5
#define T1_ 0.35f
#define T2_ 0.5f
#define ALPHA_ 0.25f
#define BETA_ 0.11f
#define BS 256

__device__ __forceinline__ float sl1(float d) {
    float x = fabsf(d);
    return (x >= BETA_) ? (x - 0.5f * BETA_) : (0.5f * x * x / BETA_);
}

// ---------------- K0: zero candidate counters + c_score ----------------
__global__ void k_init(int* __restrict__ cand_cnt, int nCnt,
                       float* __restrict__ c_score, int nScore) {
    int i = blockIdx.x * blockDim.x + threadIdx.x;
    if (i < nCnt) cand_cnt[i] = 0;
    if (i < nScore) c_score[i] = 0.f;
}

// ---------------- K1: per-prior column maxes + decode + candidate harvest ----------------
// Divide-free max tracking: a/b > c/d  <=>  a*d > c*b  (b,d > 0).
__global__ void k_per_prior(const float4* __restrict__ loc4, const float4* __restrict__ priors4,
                            const float* __restrict__ targets,
                            float* __restrict__ bt_score, float* __restrict__ cb_score,
                            int* __restrict__ btcb_idx,
                            float* __restrict__ cand_v, int* __restrict__ cand_i,
                            int* __restrict__ cand_cnt,
                            int P, int N, int CAP) {
    int b = blockIdx.y;
    int i = blockIdx.x * blockDim.x + threadIdx.x;
    __shared__ float tr[64 * 5];  // x1,y1,x2,y2,area
    for (int t = threadIdx.x; t < N; t += blockDim.x) {
        float x1 = targets[(size_t)(b * N + t) * 5 + 0];
        float y1 = targets[(size_t)(b * N + t) * 5 + 1];
        float x2 = targets[(size_t)(b * N + t) * 5 + 2];
        float y2 = targets[(size_t)(b * N + t) * 5 + 3];
        tr[t * 5 + 0] = x1; tr[t * 5 + 1] = y1;
        tr[t * 5 + 2] = x2; tr[t * 5 + 3] = y2;
        tr[t * 5 + 4] = (x2 - x1) * (y2 - y1);
    }
    __syncthreads();
    if (i >= P) return;

    float4 pr = priors4[i];
    size_t bp = (size_t)b * P + i;
    float4 lc = loc4[bp];

    float pcx = pr.x, pcy = pr.y, pw = pr.z, ph = pr.w;
    float px1 = pcx - pw * 0.5f, py1 = pcy - ph * 0.5f;
    float px2 = pcx + pw * 0.5f, py2 = pcy + ph * 0.5f;
    float pa = (px2 - px1) * (py2 - py1);  // area from rounded corners, as reference

    // stage-1: argmax_n IoU(truth_n, prior_pt), divide-free; first-max tiebreak
    float b_i = -1.f, b_u = 1.f; int bn = 0;
    for (int n = 0; n < N; n++) {
        float lx = fmaxf(tr[n * 5 + 0], px1), ly = fmaxf(tr[n * 5 + 1], py1);
        float rx = fminf(tr[n * 5 + 2], px2), ry = fminf(tr[n * 5 + 3], py2);
        float w = fmaxf(rx - lx, 0.f), h = fmaxf(ry - ly, 0.f);
        float inter = w * h;
        float uni = tr[n * 5 + 4] + pa - inter;
        bool better = inter * b_u > b_i * uni;
        b_i = better ? inter : b_i; b_u = better ? uni : b_u; bn = better ? n : bn;
    }
    float bv = b_i / b_u;

    // decode(loc, prior)
    float dcx = pcx + lc.x * VAR0_ * pw;
    float dcy = pcy + lc.y * VAR0_ * ph;
    float dw = pw * expf(lc.z * VAR1_);
    float dh = ph * expf(lc.w * VAR1_);
    float dx1 = dcx - dw * 0.5f, dy1 = dcy - dh * 0.5f;
    float dx2 = dcx + dw * 0.5f, dy2 = dcy + dh * 0.5f;
    float da = (dx2 - dx1) * (dy2 - dy1);

    // stage-2: argmax + harvest candidates with rounded v >= T2
    float c_i = -1.f, c_u = 1.f; int cn = 0;
    for (int n = 0; n < N; n++) {
        float lx = fmaxf(tr[n * 5 + 0], dx1), ly = fmaxf(tr[n * 5 + 1], dy1);
        float rx = fminf(tr[n * 5 + 2], dx2), ry = fminf(tr[n * 5 + 3], dy2);
        float w = fmaxf(rx - lx, 0.f), h = fmaxf(ry - ly, 0.f);
        float inter = w * h;
        float uni = tr[n * 5 + 4] + da - inter;
        bool better = inter * c_u > c_i * uni;
        c_i = better ? inter : c_i; c_u = better ? uni : c_u; cn = better ? n : cn;
        if (inter >= uni * 0.4999990f) {  // conservative pre-test, exact test below
            float v = inter / uni;
            if (v >= T2_) {
                int pos = atomicAdd(&cand_cnt[b * N + n], 1);
                if (pos < CAP) {
                    size_t o = (size_t)(b * N + n) * CAP + pos;
                    cand_v[o] = v; cand_i[o] = i;
                }
            }
        }
    }
    float cv = c_i / c_u;

    bt_score[bp] = bv;
    cb_score[bp] = cv;
    btcb_idx[bp] = bn | (cn << 16);
}

// ---------------- K1b: per-(b,n) row max/argmax over all priors ----------------
__global__ void k_row_max(const float4* __restrict__ priors4, const float* __restrict__ targets,
                          float* __restrict__ row_max, int* __restrict__ row_arg,
                          int P, int N) {
    int n = blockIdx.x, b = blockIdx.y;
    float tx1 = targets[(size_t)(b * N + n) * 5 + 0];
    float ty1 = targets[(size_t)(b * N + n) * 5 + 1];
    float tx2 = targets[(size_t)(b * N + n) * 5 + 2];
    float ty2 = targets[(size_t)(b * N + n) * 5 + 3];
    float ta = (tx2 - tx1) * (ty2 - ty1);
    float b_i = -1.f, b_u = 1.f; int bi = 0x7fffffff;
    for (int i = threadIdx.x; i < P; i += blockDim.x) {
        float4 pr = priors4[i];
        float px1 = pr.x - pr.z * 0.5f, py1 = pr.y - pr.w * 0.5f;
        float px2 = pr.x + pr.z * 0.5f, py2 = pr.y + pr.w * 0.5f;
        float lx = fmaxf(tx1, px1), ly = fmaxf(ty1, py1);
        float rx = fminf(tx2, px2), ry = fminf(ty2, py2);
        float w = fmaxf(rx - lx, 0.f), h = fmaxf(ry - ly, 0.f);
        float inter = w * h;
        float uni = ta + (px2 - px1) * (py2 - py1) - inter;
        bool better = inter * b_u > b_i * uni;  // strict >, increasing i -> smallest idx kept
        b_i = better ? inter : b_i; b_u = better ? uni : b_u; bi = better ? i : bi;
    }
    float bv = b_i / b_u;  // one divide per thread; reduce on rounded values (ref semantics)
    __shared__ float sv[BS];
    __shared__ int si[BS];
    int tid = threadIdx.x;
    sv[tid] = bv; si[tid] = bi;
    __syncthreads();
    for (int s = BS / 2; s > 0; s >>= 1) {
        if (tid < s) {
            if (sv[tid + s] > sv[tid] || (sv[tid + s] == sv[tid] && si[tid + s] < si[tid])) {
                sv[tid] = sv[tid + s]; si[tid] = si[tid + s];
            }
        }
        __syncthreads();
    }
    if (tid == 0) { row_max[b * N + n] = sv[0]; row_arg[b * N + n] = si[0]; }
}

// ---------------- K2: greedy bipartite matching — ONE WAVE per image, register rows ----------------
__global__ void k_greedy(const float4* __restrict__ priors4, const float* __restrict__ targets,
                         const float* __restrict__ row_max_in, const int* __restrict__ row_arg_in,
                         float* __restrict__ bt_score, int* __restrict__ btcb_idx,
                         int P, int N) {
    int b = blockIdx.x;
    int lane = threadIdx.x;  // block == 1 wave of 64
    extern __shared__ unsigned int mask[];
    int maskWords = (P + 31) >> 5;
    for (int w = lane; w < maskWords; w += 64) mask[w] = 0u;

    float rmax = -2.f; int rarg = 0x7fffffff; int alive = 0;
    float tx1 = 0.f, ty1 = 0.f, tx2 = 0.f, ty2 = 0.f, ta = 0.f;
    if (lane < N) {
        rmax = row_max_in[b * N + lane];
        rarg = row_arg_in[b * N + lane];
        alive = 1;
        tx1 = targets[(size_t)(b * N + lane) * 5 + 0];
        ty1 = targets[(size_t)(b * N + lane) * 5 + 1];
        tx2 = targets[(size_t)(b * N + lane) * 5 + 2];
        ty2 = targets[(size_t)(b * N + lane) * 5 + 3];
        ta = (tx2 - tx1) * (ty2 - ty1);
    }
    __syncthreads();

    for (int it = 0; it < N; it++) {
        // wave argmax over alive rows: (value desc, row asc)
        float v = (lane < N && alive) ? rmax : -3.f;
        int idx = lane;
#pragma unroll
        for (int off = 32; off > 0; off >>= 1) {
            float ov = __shfl_xor(v, off);
            int oi = __shfl_xor(idx, off);
            if (ov > v || (ov == v && oi < idx)) { v = ov; idx = oi; }
        }
        int bj = idx;
        float bv = v;
        int sel = __shfl(rarg, bj);
        if (lane == bj) alive = 0;
        if (lane == 0) {
            size_t bpsel = (size_t)b * P + sel;
            bt_score[bpsel] = bv;
            int wrd = btcb_idx[bpsel];
            btcb_idx[bpsel] = (wrd & ~0xFFFF) | bj;
            mask[sel >> 5] |= (1u << (sel & 31));
        }
        __syncthreads();

        // rescan rows whose cached argmax column just got masked (rare)
        unsigned long long coll = __ballot(lane < N && alive && rarg == sel);
        while (coll) {
            int r = __ffsll((long long)coll) - 1;
            coll &= coll - 1;
            float rx1 = __shfl(tx1, r), ry1 = __shfl(ty1, r);
            float rx2 = __shfl(tx2, r), ry2 = __shfl(ty2, r);
            float ra = __shfl(ta, r);
            float n_i = -2.f, n_u = 1.f; int ni = 0x7fffffff;
            for (int i = lane; i < P; i += 64) {
                if (mask[i >> 5] & (1u << (i & 31))) continue;
                float4 pr = priors4[i];
                float px1 = pr.x - pr.z * 0.5f, py1 = pr.y - pr.w * 0.5f;
                float px2 = pr.x + pr.z * 0.5f, py2 = pr.y + pr.w * 0.5f;
                float lx = fmaxf(rx1, px1), ly = fmaxf(ry1, py1);
                float rx = fminf(rx2, px2), ry = fminf(ry2, py2);
                float w = fmaxf(rx - lx, 0.f), h = fmaxf(ry - ly, 0.f);
                float inter = w * h;
                float uni = ra + (px2 - px1) * (py2 - py1) - inter;
                bool better = inter * n_u > n_i * uni;
                n_i = better ? inter : n_i; n_u = better ? uni : n_u; ni = better ? i : ni;
            }
            float nv = n_i / n_u;
#pragma unroll
            for (int off = 32; off > 0; off >>= 1) {
                float ov = __shfl_xor(nv, off);
                int oi = __shfl_xor(ni, off);
                if (ov > nv || (ov == nv && oi < ni)) { nv = ov; ni = oi; }
            }
            if (lane == r) { rmax = nv; rarg = ni; }
        }
        __syncthreads();
    }
}

// ---------------- K3: per-(b,n) top-5 of thresholded c_iou (lax.top_k semantics) ----------------
__global__ void k_topk(const float4* __restrict__ loc4, const float4* __restrict__ priors4,
                       const float* __restrict__ targets,
                       const float* __restrict__ cand_v, const int* __restrict__ cand_i,
                       const int* __restrict__ cand_cnt,
                       float* __restrict__ tk_s, int* __restrict__ tk_i,
                       int P, int N, int CAP) {
    int n = blockIdx.x, b = blockIdx.y;
    int row = b * N + n;
    int tid = threadIdx.x;

    float vals[KTOP_]; int ids[KTOP_];
#pragma unroll
    for (int k = 0; k < KTOP_; k++) { vals[k] = -1.f; ids[k] = 0x7fffffff; }

    int cnt = cand_cnt[row];
    if (cnt <= CAP) {
        for (int k = tid; k < cnt; k += blockDim.x) {
            float cv = cand_v[(size_t)row * CAP + k];
            int ci = cand_i[(size_t)row * CAP + k];
#pragma unroll
            for (int q = 0; q < KTOP_; q++) {
                bool better = (cv > vals[q]) || ((cv == vals[q]) && (ci < ids[q]));
                float tv = better ? cv : vals[q]; int ti = better ? ci : ids[q];
                cv = better ? vals[q] : cv; ci = better ? ids[q] : ci;
                vals[q] = tv; ids[q] = ti;
            }
        }
    } else {
        // deterministic fallback: full rescan of this row (overflowed candidate buffer)
        float tx1 = targets[(size_t)row * 5 + 0], ty1 = targets[(size_t)row * 5 + 1];
        float tx2 = targets[(size_t)row * 5 + 2], ty2 = targets[(size_t)row * 5 + 3];
        float ta = (tx2 - tx1) * (ty2 - ty1);
        for (int i = tid; i < P; i += blockDim.x) {
            float4 pr = priors4[i];
            size_t bp = (size_t)b * P + i;
            float4 lc = loc4[bp];
            float dcx = pr.x + lc.x * VAR0_ * pr.z;
            float dcy = pr.y + lc.y * VAR0_ * pr.w;
            float dw = pr.z * expf(lc.z * VAR1_);
            float dh = pr.w * expf(lc.w * VAR1_);
            float dx1 = dcx - dw * 0.5f, dy1 = dcy - dh * 0.5f;
            float dx2 = dcx + dw * 0.5f, dy2 = dcy + dh * 0.5f;
            float lx = fmaxf(tx1, dx1), ly = fmaxf(ty1, dy1);
            float rx = fminf(tx2, dx2), ry = fminf(ty2, dy2);
            float w = fmaxf(rx - lx, 0.f), h = fmaxf(ry - ly, 0.f);
            float inter = w * h;
            float uni = ta + (dx2 - dx1) * (dy2 - dy1) - inter;
            if (inter >= uni * 0.4999990f) {
                float v = inter / uni;
                if (v >= T2_) {
                    float cv = v; int ci = i;
#pragma unroll
                    for (int q = 0; q < KTOP_; q++) {
                        bool better = (cv > vals[q]) || ((cv == vals[q]) && (ci < ids[q]));
                        float tv = better ? cv : vals[q]; int ti = better ? ci : ids[q];
                        cv = better ? vals[q] : cv; ci = better ? ids[q] : ci;
                        vals[q] = tv; ids[q] = ti;
                    }
                }
            }
        }
    }

    __shared__ float mv[BS * KTOP_];
    __shared__ int mi[BS * KTOP_];
#pragma unroll
    for (int k = 0; k < KTOP_; k++) { mv[tid * KTOP_ + k] = vals[k]; mi[tid * KTOP_ + k] = ids[k]; }
    __syncthreads();
    for (int s = BS / 2; s > 0; s >>= 1) {
        if (tid < s) {
#pragma unroll
            for (int j = 0; j < KTOP_; j++) {
                float cv = mv[(tid + s) * KTOP_ + j];
                int ci = mi[(tid + s) * KTOP_ + j];
#pragma unroll
                for (int q = 0; q < KTOP_; q++) {
                    bool better = (cv > vals[q]) || ((cv == vals[q]) && (ci < ids[q]));
                    float tv = better ? cv : vals[q]; int ti = better ? ci : ids[q];
                    cv = better ? vals[q] : cv; ci = better ? ids[q] : ci;
                    vals[q] = tv; ids[q] = ti;
                }
            }
#pragma unroll
            for (int k = 0; k < KTOP_; k++) { mv[tid * KTOP_ + k] = vals[k]; mi[tid * KTOP_ + k] = ids[k]; }
        }
        __syncthreads();
    }
    if (tid == 0) {
#pragma unroll
        for (int k = 0; k < KTOP_; k++) {
            tk_s[(size_t)row * KTOP_ + k] = (vals[k] > 0.f) ? vals[k] : 0.f;
            tk_i[(size_t)row * KTOP_ + k] = (ids[k] == 0x7fffffff) ? 0 : ids[k];
        }
    }
}

// ---------------- K3b: assign loop, parallel last-writer-wins ----------------
__global__ void k_assign(const float* __restrict__ targets,
                         const float* __restrict__ tk_s, const int* __restrict__ tk_i,
                         const float* __restrict__ bt_score, const int* __restrict__ btcb_idx,
                         int* __restrict__ cb_idx2, float* __restrict__ c_score,
                         int P, int N) {
    int b = blockIdx.x;
    int tid = threadIdx.x;
    int T = N * KTOP_;  // 160
    __shared__ int sh_p[512];
    __shared__ float sh_s[512];
    __shared__ int sh_c[512];
    if (tid < T) {
        int i = tid / KTOP_, j = tid % KTOP_;
        int p = tk_i[(size_t)(b * N + i) * KTOP_ + j];
        float s = tk_s[(size_t)(b * N + i) * KTOP_ + j];
        size_t bp = (size_t)b * P + p;
        float bs = bt_score[bp];
        int bj = btcb_idx[bp] & 0xFFFF;
        float conf1 = (bs < T1_) ? 0.f : targets[(size_t)(b * N + bj) * 5 + 4];
        sh_p[tid] = p; sh_s[tid] = s;
        sh_c[tid] = (conf1 < 1.f && s > 0.f) ? 1 : 0;
    }
    __syncthreads();
    if (tid < T && sh_c[tid]) {
        int p = sh_p[tid];
        bool last = true;
        for (int t2 = tid + 1; t2 < T; t2++) {
            if (sh_c[t2] && sh_p[t2] == p) { last = false; break; }
        }
        if (last) {
            size_t bp = (size_t)b * P + p;
            cb_idx2[bp] = tid / KTOP_;
            c_score[bp] = sh_s[tid];
        }
    }
}

// ---------------- K4: per-element losses + block partial sums ----------------
__global__ void k_loss(const float4* __restrict__ loc4, const float* __restrict__ conf,
                       const float4* __restrict__ priors4, const float* __restrict__ targets,
                       const float* __restrict__ bt_score, const int* __restrict__ btcb_idx,
                       const float* __restrict__ cb_score, const int* __restrict__ cb_idx2,
                       const float* __restrict__ c_score,
                       double* __restrict__ partials,
                       int P, int N, int C) {
    int b = blockIdx.y;
    int i = blockIdx.x * blockDim.x + threadIdx.x;
    double l1 = 0.0, l2 = 0.0, f1 = 0.0, f2 = 0.0;
    int n1 = 0, n2 = 0;
    if (i < P) {
        size_t bp = (size_t)b * P + i;
        float bs = bt_score[bp];
        int widx = btcb_idx[bp];
        int bj = widx & 0xFFFF;
        float cbs = cb_score[bp]; float cs = c_score[bp];
        int cj = (cs > 0.f) ? cb_idx2[bp] : ((widx >> 16) & 0xFFFF);
        float lab1 = targets[(size_t)(b * N + bj) * 5 + 4];
        float conf1 = (bs < T1_) ? 0.f : lab1;
        if ((bs < T1_) && (cbs >= T2_) && (cs < T2_)) conf1 = -1.f;
        float lab2 = targets[(size_t)(b * N + cj) * 5 + 4];
        float conf2 = (cs < T2_) ? -1.f : lab2;
        bool m1 = conf1 > 0.f, m2 = conf2 > 0.f;
        n1 = m1 ? 1 : 0; n2 = m2 ? 1 : 0;

        float4 pr = priors4[i];
        float pcx = pr.x, pcy = pr.y, pw = pr.z, ph = pr.w;
        float4 lc = loc4[bp];
        float p0 = lc.x, p1 = lc.y, p2 = lc.z, p3 = lc.w;

        if (m1) {
            const float* tb = &targets[(size_t)(b * N + bj) * 5];
            float gx = ((tb[0] + tb[2]) * 0.5f - pcx) / (VAR0_ * pw);
            float gy = ((tb[1] + tb[3]) * 0.5f - pcy) / (VAR0_ * ph);
            float gw = logf((tb[2] - tb[0]) / pw) / VAR1_;
            float gh = logf((tb[3] - tb[1]) / ph) / VAR1_;
            l1 = (double)(sl1(p0 - gx) + sl1(p1 - gy) + sl1(p2 - gw) + sl1(p3 - gh));
        }
        if (m2) {
            const float* tb = &targets[(size_t)(b * N + cj) * 5];
            float gx = ((tb[0] + tb[2]) * 0.5f - pcx) / (VAR0_ * pw);
            float gy = ((tb[1] + tb[3]) * 0.5f - pcy) / (VAR0_ * ph);
            float gw = logf((tb[2] - tb[0]) / pw) / VAR1_;
            float gh = logf((tb[3] - tb[1]) / ph) / VAR1_;
            l2 = (double)(sl1(p0 - gx) + sl1(p1 - gy) + sl1(p2 - gw) + sl1(p3 - gh));
        }
        {   // focal 1
            float t = fmaxf(conf1, 0.f);
            float keep = (conf1 >= 0.f) ? 1.f : 0.f;
            int cls = (int)t;
            float x = conf[bp * C + cls];
            float ce = fmaxf(x, 0.f) - x * t + log1pf(expf(-fabsf(x)));
            float a = t * ALPHA_ + (1.f - t) * (1.f - ALPHA_);
            float pr_ = 1.f / (1.f + expf(-x));
            float pt = (t == 1.f) ? pr_ : (1.f - pr_);
            float om = 1.f - pt;
            f1 = (double)(a * om * om * ce * keep);
        }
        {   // focal 2 (iou-weighted)
            float t = fmaxf(conf2, 0.f);
            float keep = (conf2 >= 0.f) ? 1.f : 0.f;
            int cls = (int)t;
            float x = conf[bp * C + cls];
            float ce = fmaxf(x, 0.f) - x * t + log1pf(expf(-fabsf(x)));
            float a = cs * (t * ALPHA_ + (1.f - t) * (1.f - ALPHA_));
            float pr_ = 1.f / (1.f + expf(-x));
            float pt = (t == 1.f) ? pr_ : (1.f - pr_);
            float om = 1.f - pt;
            f2 = (double)(a * om * om * ce * keep);
        }
    }
    __shared__ double sd[BS * 4];
    __shared__ int sn[BS * 2];
    int tid = threadIdx.x;
    sd[tid * 4 + 0] = l1; sd[tid * 4 + 1] = l2; sd[tid * 4 + 2] = f1; sd[tid * 4 + 3] = f2;
    sn[tid * 2 + 0] = n1; sn[tid * 2 + 1] = n2;
    __syncthreads();
    for (int s = BS / 2; s > 0; s >>= 1) {
        if (tid < s) {
            sd[tid * 4 + 0] += sd[(tid + s) * 4 + 0];
            sd[tid * 4 + 1] += sd[(tid + s) * 4 + 1];
            sd[tid * 4 + 2] += sd[(tid + s) * 4 + 2];
            sd[tid * 4 + 3] += sd[(tid + s) * 4 + 3];
            sn[tid * 2 + 0] += sn[(tid + s) * 2 + 0];
            sn[tid * 2 + 1] += sn[(tid + s) * 2 + 1];
        }
        __syncthreads();
    }
    if (tid == 0) {
        int blk = blockIdx.y * gridDim.x + blockIdx.x;
        partials[(size_t)blk * 6 + 0] = sd[0];
        partials[(size_t)blk * 6 + 1] = sd[1];
        partials[(size_t)blk * 6 + 2] = sd[2];
        partials[(size_t)blk * 6 + 3] = sd[3];
        partials[(size_t)blk * 6 + 4] = (double)sn[0];
        partials[(size_t)blk * 6 + 5] = (double)sn[1];
    }
}

// ---------------- K5: final reduction + loss assembly ----------------
__global__ void k_final(const double* __restrict__ partials, int nPart, float* __restrict__ out) {
    int tid = threadIdx.x;
    double a[6] = {0, 0, 0, 0, 0, 0};
    for (int k = tid; k < nPart; k += BS) {
#pragma unroll
        for (int j = 0; j < 6; j++) a[j] += partials[(size_t)k * 6 + j];
    }
    __shared__ double sd[BS * 6];
#pragma unroll
    for (int j = 0; j < 6; j++) sd[tid * 6 + j] = a[j];
    __syncthreads();
    for (int s = BS / 2; s > 0; s >>= 1) {
        if (tid < s) {
#pragma unroll
            for (int j = 0; j < 6; j++) sd[tid * 6 + j] += sd[(tid + s) * 6 + j];
        }
        __syncthreads();
    }
    if (tid == 0) {
        double L1 = sd[0], L2 = sd[1], F1 = sd[2], F2 = sd[3], N1 = sd[4], N2 = sd[5];
        double l1v = L1 / fmax(N1, 1.0), l2v = L2 / fmax(N2, 1.0);
        double f1v = F1 / fmax(N1, 1.0), f2v = F2 / fmax(N2, 1.0);
        double locl = (N1 > 0 ? l1v : 0.0) + (N2 > 0 ? l2v : 0.0);
        double clsl = (N1 > 0 ? f1v : 0.0) + (N2 > 0 ? f2v : 0.0);
        if (N1 == 0 && N2 == 0) { locl = 1e-4; clsl = 1e-4; }
        out[0] = (float)locl;
        out[1] = (float)clsl;
    }
}

extern "C" void kernel_launch(void* const* d_in, const int* in_sizes, int n_in,
                              void* d_out, int out_size, void* d_ws, size_t ws_size,
                              hipStream_t stream) {
    const float* targets = (const float*)d_in[3];
    const float* conf = (const float*)d_in[1];
    const float4* loc4 = (const float4*)d_in[0];
    const float4* priors4 = (const float4*)d_in[2];

    int P = in_sizes[2] / 4;
    int B = in_sizes[0] / (P * 4);
    int N = in_sizes[3] / (B * 5);
    int C = in_sizes[1] / (B * P);
    const int CAP = 2048;
    size_t BP = (size_t)B * P;

    unsigned char* ws = (unsigned char*)d_ws;
    size_t off = 0;
    auto alloc = [&](size_t bytes) { size_t cur = off; off += (bytes + 255) & ~(size_t)255; return cur; };
    float* bt_score = (float*)(ws + alloc(BP * 4));
    float* cb_score = (float*)(ws + alloc(BP * 4));
    int* btcb_idx = (int*)(ws + alloc(BP * 4));
    int* cb_idx2 = (int*)(ws + alloc(BP * 4));
    float* c_score = (float*)(ws + alloc(BP * 4));
    float* row_max = (float*)(ws + alloc((size_t)B * N * 4));
    int* row_arg = (int*)(ws + alloc((size_t)B * N * 4));
    float* tk_s = (float*)(ws + alloc((size_t)B * N * KTOP_ * 4));
    int* tk_i = (int*)(ws + alloc((size_t)B * N * KTOP_ * 4));
    float* cand_v = (float*)(ws + alloc((size_t)B * N * CAP * 4));
    int* cand_i = (int*)(ws + alloc((size_t)B * N * CAP * 4));
    int* cand_cnt = (int*)(ws + alloc((size_t)B * N * 4));
    int bx = (P + BS - 1) / BS;
    double* partials = (double*)(ws + alloc((size_t)bx * B * 6 * 8));
    float* out = (float*)d_out;

    k_init<<<dim3((int)((BP + BS - 1) / BS)), dim3(BS), 0, stream>>>(cand_cnt, B * N, c_score, (int)BP);
    dim3 g1(bx, B);
    k_per_prior<<<g1, BS, 0, stream>>>(loc4, priors4, targets, bt_score, cb_score, btcb_idx,
                                       cand_v, cand_i, cand_cnt, P, N, CAP);
    k_row_max<<<dim3(N, B), BS, 0, stream>>>(priors4, targets, row_max, row_arg, P, N);
    int maskWords = (P + 31) / 32;
    size_t shmem = (size_t)maskWords * 4;
    k_greedy<<<dim3(B), 64, shmem, stream>>>(priors4, targets, row_max, row_arg,
                                             bt_score, btcb_idx, P, N);
    k_topk<<<dim3(N, B), BS, 0, stream>>>(loc4, priors4, targets, cand_v, cand_i, cand_cnt,
                                          tk_s, tk_i, P, N, CAP);
    k_assign<<<dim3(B), BS, 0, stream>>>(targets, tk_s, tk_i, bt_score, btcb_idx,
                                         cb_idx2, c_score, P, N);
    k_loss<<<g1, BS, 0, stream>>>(loc4, conf, priors4, targets, bt_score, btcb_idx,
                                  cb_score, cb_idx2, c_score, partials, P, N, C);
    k_final<<<1, BS, 0, stream>>>(partials, bx * B, out);
}